// Round 1
// baseline (110.433 us; speedup 1.0000x reference)
//
#include <hip/hip_runtime.h>

// Problem constants (from reference): B=128, T=256, IN=1, H=5000, OUT=20
#define T_STEPS 256
#define BATCH   128
#define HIDDEN  5000
#define NOUT    20
#define HB      256   // hidden units per block (== blockDim.x)

// ---------------------------------------------------------------------------
// Kernel 1: the recurrence. One thread owns one (b, i) chain:
//     h <- tanh(x[b,t]*w[i] + bias[i] + h),  t = 0..255
// We track hc = c*h with c = 2*log2(e), so that
//     tanh(z) = 1 - 2/(exp2(c*z)+1),   c*z = fma(x, w*c, hc + bias*c)
// per step: add, fma, exp2, add, rcp, fma  (2 transcendental, 4 plain VALU)
// ---------------------------------------------------------------------------
__global__ __launch_bounds__(256, 8)
void rnn_recurrence(const float* __restrict__ x,
                    const float* __restrict__ W_in,
                    const float* __restrict__ b_in,
                    float* __restrict__ h_out) {
    __shared__ float xs[T_STEPS];
    const int hb  = blockIdx.x;
    const int b   = blockIdx.y;
    const int tid = threadIdx.x;

    // stage this batch row of x into LDS (broadcast source for all chains)
    xs[tid] = x[b * T_STEPS + tid];
    __syncthreads();

    const int hidx = hb * HB + tid;
    if (hidx < HIDDEN) {
        const float c     = 2.8853900817779268f;   // 2*log2(e)
        const float inv_c = 0.34657359027997264f;  // ln(2)/2
        const float wc = W_in[hidx] * c;
        const float bc = b_in[hidx] * c;
        float hc = 0.0f;                            // h0 = 0
        #pragma unroll 8
        for (int t = 0; t < T_STEPS; ++t) {
            float u = fmaf(xs[t], wc, hc + bc);     // c*(x*w + b + h)
            float e = __builtin_amdgcn_exp2f(u);    // e^{2z}
            float r = __builtin_amdgcn_rcpf(e + 1.0f);
            hc = fmaf(-2.0f * c, r, c);             // c * tanh(z)
        }
        h_out[b * HIDDEN + hidx] = hc * inv_c;
    }
}

// ---------------------------------------------------------------------------
// Kernel 2: logits = h_final @ W_out^T + b_out, then 20-wide softmax.
// One block per batch row; 256 threads strided over H with 20 accumulators.
// W_out rows are read coalesced (lane i -> consecutive h), all L2-hot.
// ---------------------------------------------------------------------------
__global__ __launch_bounds__(256)
void head_softmax(const float* __restrict__ h,
                  const float* __restrict__ W_out,
                  const float* __restrict__ b_out,
                  float* __restrict__ out) {
    const int b   = blockIdx.x;
    const int tid = threadIdx.x;

    float acc[NOUT];
    #pragma unroll
    for (int o = 0; o < NOUT; ++o) acc[o] = 0.0f;

    for (int i = tid; i < HIDDEN; i += 256) {
        const float hv = h[b * HIDDEN + i];
        #pragma unroll
        for (int o = 0; o < NOUT; ++o)
            acc[o] = fmaf(hv, W_out[o * HIDDEN + i], acc[o]);
    }

    // reduce across the 64-lane wave
    #pragma unroll
    for (int o = 0; o < NOUT; ++o) {
        #pragma unroll
        for (int s = 32; s > 0; s >>= 1)
            acc[o] += __shfl_down(acc[o], s, 64);
    }

    __shared__ float partial[4][NOUT];
    const int wid = tid >> 6, lane = tid & 63;
    if (lane == 0) {
        #pragma unroll
        for (int o = 0; o < NOUT; ++o) partial[wid][o] = acc[o];
    }
    __syncthreads();

    if (tid == 0) {
        float logits[NOUT];
        float m = -1e30f;
        #pragma unroll
        for (int o = 0; o < NOUT; ++o) {
            float v = partial[0][o] + partial[1][o] + partial[2][o]
                    + partial[3][o] + b_out[o];
            logits[o] = v;
            m = fmaxf(m, v);
        }
        float s = 0.0f;
        float e[NOUT];
        #pragma unroll
        for (int o = 0; o < NOUT; ++o) {
            e[o] = __builtin_amdgcn_exp2f((logits[o] - m) * 1.4426950408889634f);
            s += e[o];
        }
        const float inv = 1.0f / s;
        #pragma unroll
        for (int o = 0; o < NOUT; ++o) out[b * NOUT + o] = e[o] * inv;
    }
}

extern "C" void kernel_launch(void* const* d_in, const int* in_sizes, int n_in,
                              void* d_out, int out_size, void* d_ws, size_t ws_size,
                              hipStream_t stream) {
    const float* x     = (const float*)d_in[0];
    const float* W_in  = (const float*)d_in[1];
    const float* b_in  = (const float*)d_in[2];
    const float* W_out = (const float*)d_in[3];
    const float* b_out = (const float*)d_in[4];
    float* out  = (float*)d_out;
    float* h_ws = (float*)d_ws;   // [BATCH][HIDDEN] f32 = 2.56 MB

    dim3 grid1((HIDDEN + HB - 1) / HB, BATCH);
    rnn_recurrence<<<grid1, 256, 0, stream>>>(x, W_in, b_in, h_ws);
    head_softmax<<<BATCH, 256, 0, stream>>>(h_ws, W_out, b_out, out);
}

// Round 2
// 102.086 us; speedup vs baseline: 1.0818x; 1.0818x over previous
//
#include <hip/hip_runtime.h>

// Problem constants (from reference): B=128, T=256, IN=1, H=5000, OUT=20
#define T_STEPS 256
#define BATCH   128
#define HIDDEN  5000
#define NHALF   2500   // 2 chains per thread: i and i+NHALF
#define NOUT    20

// ---------------------------------------------------------------------------
// Kernel 1: recurrence  h <- tanh(x_t*w + b + h).
// Tracking hc = c*h with c = 2*log2(e):
//   tanh(z) = 1 - 2/(exp2(c*z)+1)
//   c*z = c*(x*w + h) + c*b  ->  E = exp2(fma(x,wc,hc)) * K,  K = exp2(c*b)
// per chain-step: fma, exp2, fma, rcp, fma  = 3 main + 2 trans (22 cyc issue)
// Two independent chains per thread (i, i+2500):
//   - same batch row => one wave-uniform x scalar (s_load, no LDS/ds_read)
//   - 2x ILP hides the dependent-chain latency
// Grid: 10 x 128 = 1280 blocks, ~5 blocks/CU, 20 waves/CU, all co-resident
// (no second dispatch round => no occupancy tail).
// ---------------------------------------------------------------------------
__global__ __launch_bounds__(256)
void rnn_recurrence(const float* __restrict__ x,
                    const float* __restrict__ W_in,
                    const float* __restrict__ b_in,
                    float* __restrict__ h_out) {
    const int b  = blockIdx.y;
    const int i0 = blockIdx.x * 256 + threadIdx.x;
    if (i0 >= NHALF) return;
    const int i1 = i0 + NHALF;

    const float c     = 2.8853900817779268f;   // 2*log2(e)
    const float inv_c = 0.34657359027997264f;  // ln(2)/2
    const float n2c   = -5.7707801635558537f;  // -2c

    const float wc0 = W_in[i0] * c;
    const float wc1 = W_in[i1] * c;
    const float K0  = __builtin_amdgcn_exp2f(b_in[i0] * c);
    const float K1  = __builtin_amdgcn_exp2f(b_in[i1] * c);

    const float* __restrict__ xrow = x + b * T_STEPS;  // wave-uniform reads

    float hc0 = 0.0f, hc1 = 0.0f;   // h0 = 0
    #pragma unroll 16
    for (int t = 0; t < T_STEPS; ++t) {
        const float xv = xrow[t];                       // s_load (uniform)
        float u0 = fmaf(xv, wc0, hc0);
        float u1 = fmaf(xv, wc1, hc1);
        float e0 = __builtin_amdgcn_exp2f(u0);
        float e1 = __builtin_amdgcn_exp2f(u1);
        float d0 = fmaf(e0, K0, 1.0f);
        float d1 = fmaf(e1, K1, 1.0f);
        float r0 = __builtin_amdgcn_rcpf(d0);
        float r1 = __builtin_amdgcn_rcpf(d1);
        hc0 = fmaf(r0, n2c, c);                         // c * tanh(z)
        hc1 = fmaf(r1, n2c, c);
    }
    h_out[b * HIDDEN + i0] = hc0 * inv_c;
    h_out[b * HIDDEN + i1] = hc1 * inv_c;
}

// ---------------------------------------------------------------------------
// Kernel 2: logits = h @ W_out^T + b_out, softmax over 20.
// One block per batch row; float4 loads (5000 = 1250 float4 exactly).
// ---------------------------------------------------------------------------
__global__ __launch_bounds__(256)
void head_softmax(const float* __restrict__ h,
                  const float* __restrict__ W_out,
                  const float* __restrict__ b_out,
                  float* __restrict__ out) {
    const int b   = blockIdx.x;
    const int tid = threadIdx.x;

    const float4* __restrict__ h4 = (const float4*)(h + b * HIDDEN);
    const float4* __restrict__ w4 = (const float4*)W_out;

    float acc[NOUT];
    #pragma unroll
    for (int o = 0; o < NOUT; ++o) acc[o] = 0.0f;

    for (int i4 = tid; i4 < HIDDEN / 4; i4 += 256) {
        const float4 hv = h4[i4];
        #pragma unroll
        for (int o = 0; o < NOUT; ++o) {
            const float4 wv = w4[o * (HIDDEN / 4) + i4];
            acc[o] = fmaf(hv.x, wv.x, acc[o]);
            acc[o] = fmaf(hv.y, wv.y, acc[o]);
            acc[o] = fmaf(hv.z, wv.z, acc[o]);
            acc[o] = fmaf(hv.w, wv.w, acc[o]);
        }
    }

    // reduce across the 64-lane wave
    #pragma unroll
    for (int o = 0; o < NOUT; ++o) {
        #pragma unroll
        for (int s = 32; s > 0; s >>= 1)
            acc[o] += __shfl_down(acc[o], s, 64);
    }

    __shared__ float partial[4][NOUT];
    const int wid = tid >> 6, lane = tid & 63;
    if (lane == 0) {
        #pragma unroll
        for (int o = 0; o < NOUT; ++o) partial[wid][o] = acc[o];
    }
    __syncthreads();

    if (tid == 0) {
        float logits[NOUT];
        float m = -1e30f;
        #pragma unroll
        for (int o = 0; o < NOUT; ++o) {
            float v = partial[0][o] + partial[1][o] + partial[2][o]
                    + partial[3][o] + b_out[o];
            logits[o] = v;
            m = fmaxf(m, v);
        }
        float s = 0.0f;
        float e[NOUT];
        #pragma unroll
        for (int o = 0; o < NOUT; ++o) {
            e[o] = __builtin_amdgcn_exp2f((logits[o] - m) * 1.4426950408889634f);
            s += e[o];
        }
        const float inv = 1.0f / s;
        #pragma unroll
        for (int o = 0; o < NOUT; ++o) out[b * NOUT + o] = e[o] * inv;
    }
}

extern "C" void kernel_launch(void* const* d_in, const int* in_sizes, int n_in,
                              void* d_out, int out_size, void* d_ws, size_t ws_size,
                              hipStream_t stream) {
    const float* x     = (const float*)d_in[0];
    const float* W_in  = (const float*)d_in[1];
    const float* b_in  = (const float*)d_in[2];
    const float* W_out = (const float*)d_in[3];
    const float* b_out = (const float*)d_in[4];
    float* out  = (float*)d_out;
    float* h_ws = (float*)d_ws;   // [BATCH][HIDDEN] f32 = 2.56 MB

    dim3 grid1((NHALF + 255) / 256, BATCH);   // 10 x 128
    rnn_recurrence<<<grid1, 256, 0, stream>>>(x, W_in, b_in, h_ws);
    head_softmax<<<BATCH, 256, 0, stream>>>(h_ws, W_out, b_out, out);
}

// Round 3
// 97.826 us; speedup vs baseline: 1.1289x; 1.0435x over previous
//
#include <hip/hip_runtime.h>

// Problem constants (from reference): B=128, T=256, IN=1, H=5000, OUT=20
#define T_STEPS 256
#define BATCH   128
#define HIDDEN  5000
#define NHALF   2500   // 2 chains per thread: i and i+NHALF
#define NOUT    20
#define NBLK    10     // gridDim.x of the fused kernel

// ---------------------------------------------------------------------------
// Fused kernel: recurrence + head partial-GEMV.
//   h <- tanh(x_t*w + b + h), tracked as hc = c*h with c = 2*log2(e):
//   tanh(z) = 1 - 2/(exp2(c*z)+1);  E = exp2(fma(x,wc,hc)) * K, K = exp2(c*b)
//   per chain-step: fma, exp2, fma, rcp, fma = 3 main + 2 trans.
//   Trans pipe (8 cyc/wave64 op) is the bound: 16 cyc/chain-step -> ~17 us.
// Then each thread folds its 2 final h values into 20 partial logits
// (coalesced W_out reads, L2-hot), block-reduces (shfl + LDS), and writes
// 20 partials per block to d_ws. No atomics, no zero-init required.
// Grid: 10 x 128 = 1280 blocks = 5 blocks/CU, 20 waves/CU, one dispatch round.
// ---------------------------------------------------------------------------
__global__ __launch_bounds__(256)
void rnn_fused(const float* __restrict__ x,
               const float* __restrict__ W_in,
               const float* __restrict__ b_in,
               const float* __restrict__ W_out,
               float* __restrict__ part) {
    const int b   = blockIdx.y;
    const int tid = threadIdx.x;
    const int i0  = blockIdx.x * 256 + tid;
    const bool valid = (i0 < NHALF);
    const int j0 = valid ? i0 : 0;            // safe index for tail lanes
    const int j1 = j0 + NHALF;

    const float c     = 2.8853900817779268f;   // 2*log2(e)
    const float inv_c = 0.34657359027997264f;  // ln(2)/2
    const float n2c   = -5.7707801635558537f;  // -2c

    const float wc0 = W_in[j0] * c;
    const float wc1 = W_in[j1] * c;
    const float K0  = __builtin_amdgcn_exp2f(b_in[j0] * c);
    const float K1  = __builtin_amdgcn_exp2f(b_in[j1] * c);

    const float* __restrict__ xrow = x + b * T_STEPS;  // wave-uniform reads

    float hc0 = 0.0f, hc1 = 0.0f;   // h0 = 0
    #pragma unroll 16
    for (int t = 0; t < T_STEPS; ++t) {
        const float xv = xrow[t];                       // uniform -> s_load
        float u0 = fmaf(xv, wc0, hc0);
        float u1 = fmaf(xv, wc1, hc1);
        float e0 = __builtin_amdgcn_exp2f(u0);
        float e1 = __builtin_amdgcn_exp2f(u1);
        float d0 = fmaf(e0, K0, 1.0f);
        float d1 = fmaf(e1, K1, 1.0f);
        float r0 = __builtin_amdgcn_rcpf(d0);
        float r1 = __builtin_amdgcn_rcpf(d1);
        hc0 = fmaf(r0, n2c, c);                         // c * tanh(z)
        hc1 = fmaf(r1, n2c, c);
    }
    const float h0 = valid ? hc0 * inv_c : 0.0f;
    const float h1 = valid ? hc1 * inv_c : 0.0f;

    // ---- head partials: acc[o] = h0*W_out[o][j0] + h1*W_out[o][j1] ----
    float acc[NOUT];
    #pragma unroll
    for (int o = 0; o < NOUT; ++o) {
        const float w0 = W_out[o * HIDDEN + j0];        // lane-coalesced
        const float w1 = W_out[o * HIDDEN + j1];
        acc[o] = fmaf(h0, w0, h1 * w1);                 // tail lanes: h==0
    }

    // wave reduce (64 lanes)
    #pragma unroll
    for (int o = 0; o < NOUT; ++o) {
        #pragma unroll
        for (int s = 32; s > 0; s >>= 1)
            acc[o] += __shfl_down(acc[o], s, 64);
    }

    __shared__ float red[4][NOUT];
    const int wid = tid >> 6, lane = tid & 63;
    if (lane == 0) {
        #pragma unroll
        for (int o = 0; o < NOUT; ++o) red[wid][o] = acc[o];
    }
    __syncthreads();

    if (tid < NOUT) {
        const float v = red[0][tid] + red[1][tid] + red[2][tid] + red[3][tid];
        part[(b * NBLK + blockIdx.x) * NOUT + tid] = v;
    }
}

// ---------------------------------------------------------------------------
// Tiny epilogue: logits[b][o] = sum_blk part + b_out[o]; softmax over 20.
// One wave per batch row; lanes 20..63 padded (-inf for max, 0 for sum).
// ---------------------------------------------------------------------------
__global__ __launch_bounds__(64)
void softmax_head(const float* __restrict__ part,
                  const float* __restrict__ b_out,
                  float* __restrict__ out) {
    const int b = blockIdx.x;
    const int o = threadIdx.x;

    float v = -1e30f;
    if (o < NOUT) {
        float s = b_out[o];
        #pragma unroll
        for (int blk = 0; blk < NBLK; ++blk)
            s += part[(b * NBLK + blk) * NOUT + o];
        v = s;
    }

    float m = v;
    #pragma unroll
    for (int s = 32; s > 0; s >>= 1) m = fmaxf(m, __shfl_xor(m, s, 64));

    float e = (o < NOUT)
            ? __builtin_amdgcn_exp2f((v - m) * 1.4426950408889634f)
            : 0.0f;
    float ssum = e;
    #pragma unroll
    for (int s = 32; s > 0; s >>= 1) ssum += __shfl_xor(ssum, s, 64);

    if (o < NOUT) out[b * NOUT + o] = e / ssum;
}

extern "C" void kernel_launch(void* const* d_in, const int* in_sizes, int n_in,
                              void* d_out, int out_size, void* d_ws, size_t ws_size,
                              hipStream_t stream) {
    const float* x     = (const float*)d_in[0];
    const float* W_in  = (const float*)d_in[1];
    const float* b_in  = (const float*)d_in[2];
    const float* W_out = (const float*)d_in[3];
    const float* b_out = (const float*)d_in[4];
    float* out  = (float*)d_out;
    float* part = (float*)d_ws;   // [BATCH][NBLK][NOUT] f32 = 102 KB

    dim3 grid1(NBLK, BATCH);      // 10 x 128
    rnn_fused<<<grid1, 256, 0, stream>>>(x, W_in, b_in, W_out, part);
    softmax_head<<<BATCH, 64, 0, stream>>>(part, b_out, out);
}